// Round 1
// baseline (287.333 us; speedup 1.0000x reference)
//
#include <hip/hip_runtime.h>
#include <cmath>

// Problem constants (fixed by reference file)
#define B_     8
#define NH_    32
#define HD_    128
#define HID_   4096
#define MAXS_  4096
#define NPAIR_ (B_ * NH_)          // 256 (b,h) pairs
#define NUNIT_ (MAXS_ / 128)       // 32 wave-units of 128 keys each
#define PSTR_  132                 // partial stride: m, l, pad, pad, acc[128]
#define PART_OFF_ (3 * B_ * HID_)  // 98304 floats: q,k,v
#define ATTN_OFF_ (PART_OFF_ + NPAIR_ * NUNIT_ * PSTR_)
#define NEG_BIG_ (-1e30f)

__device__ __forceinline__ float dot4(float4 a, float4 b) {
  return a.x * b.x + a.y * b.y + a.z * b.z + a.w * b.w;
}

// out[b][row] = sum_j W[row][j] * x[b][j]   for W in {W0,W1,W2} chosen by blockIdx>>8.
// 16 rows/block (4 rows/wave), j split: lane covers j = u*256 + lane*4 .. +3, u=0..15.
__global__ __launch_bounds__(256) void gemv_rows(
    const float* __restrict__ W0, const float* __restrict__ W1,
    const float* __restrict__ W2, const float* __restrict__ x,
    float* __restrict__ out)
{
  const int bid = blockIdx.x;
  const int m   = bid >> 8;               // matrix index (0..2); grid 256 -> always 0
  const int rb  = (bid & 255) << 4;       // first of 16 rows
  const float* __restrict__ W = (m == 0) ? W0 : ((m == 1) ? W1 : W2);
  float* o = out + m * (B_ * HID_);

  const int wib  = threadIdx.x >> 6;
  const int lane = threadIdx.x & 63;
  const int r0   = rb + wib * 4;

  float acc[4][8];
#pragma unroll
  for (int r = 0; r < 4; ++r)
#pragma unroll
    for (int b = 0; b < 8; ++b) acc[r][b] = 0.f;

  const float* Wp = W + (size_t)r0 * HID_ + lane * 4;
#pragma unroll 2
  for (int u = 0; u < 16; ++u) {
    const int j = u * 256;
    float4 w0 = *(const float4*)(Wp + j);
    float4 w1 = *(const float4*)(Wp + j + HID_);
    float4 w2 = *(const float4*)(Wp + j + 2 * HID_);
    float4 w3 = *(const float4*)(Wp + j + 3 * HID_);
#pragma unroll
    for (int b = 0; b < 8; ++b) {
      float4 xb = *(const float4*)(x + b * HID_ + j + lane * 4);
      acc[0][b] += dot4(w0, xb);
      acc[1][b] += dot4(w1, xb);
      acc[2][b] += dot4(w2, xb);
      acc[3][b] += dot4(w3, xb);
    }
  }

  // butterfly reduce each of the 32 partials across the 64-lane wave
#pragma unroll
  for (int r = 0; r < 4; ++r)
#pragma unroll
    for (int b = 0; b < 8; ++b) {
      float v = acc[r][b];
#pragma unroll
      for (int off = 32; off; off >>= 1) v += __shfl_xor(v, off);
      acc[r][b] = v;
    }

  if (lane == 0) {
#pragma unroll
    for (int r = 0; r < 4; ++r)
#pragma unroll
      for (int b = 0; b < 8; ++b)
        o[(size_t)b * HID_ + r0 + r] = acc[r][b];
  }
}

// Flash-decoding partials. One 64-lane wave handles 128 keys of one (b,h).
// Halves (32 lanes) process adjacent keys; lane covers dims l32*4..+3 (float4).
// Key index == pos uses fresh k/v from workspace (inputs never mutated).
__global__ __launch_bounds__(256) void attn_partial(
    const float* __restrict__ qkv, const float* __restrict__ ck,
    const float* __restrict__ cv, const int* __restrict__ ppos,
    float* __restrict__ part)
{
  const int pos  = *ppos;
  const int wib  = threadIdx.x >> 6;
  const int lane = threadIdx.x & 63;
  const int unit = blockIdx.x * 4 + wib;
  const int pair = unit >> 5;            // / NUNIT_
  const int u    = unit & (NUNIT_ - 1);
  const int b    = pair >> 5;            // / NH_
  const int h    = pair & (NH_ - 1);
  float* pb = part + (size_t)(pair * NUNIT_ + u) * PSTR_;
  const int k0 = u * 128;

  if (k0 > pos) {                        // unit entirely past the sequence
    if (lane == 0) { pb[0] = NEG_BIG_; pb[1] = 0.f; }
    return;
  }

  const int half = lane >> 5, l32 = lane & 31;
  const float scale = 0.08838834764831845f;   // 1/sqrt(128)

  float4 q4 = *(const float4*)(qkv + b * HID_ + h * HD_ + l32 * 4);
  q4.x *= scale; q4.y *= scale; q4.z *= scale; q4.w *= scale;

  const float* kfresh = qkv + B_ * HID_     + b * HID_ + h * HD_;
  const float* vfresh = qkv + 2 * B_ * HID_ + b * HID_ + h * HD_;
  const float* ckh = ck + (((size_t)b * NH_ + h) * MAXS_) * HD_;
  const float* cvh = cv + (((size_t)b * NH_ + h) * MAXS_) * HD_;

  float m = NEG_BIG_, l = 0.f;
  float4 acc = make_float4(0.f, 0.f, 0.f, 0.f);

#pragma unroll 2
  for (int i = 0; i < 64; ++i) {
    const int ki = k0 + 2 * i + half;
    const bool act = (ki <= pos);        // uniform within each 32-lane half
    float s = 0.f;
    if (act) {
      const float* kp = (ki == pos) ? kfresh : (ckh + (size_t)ki * HD_);
      float4 k4 = *(const float4*)(kp + l32 * 4);
      s = dot4(q4, k4);
    }
    // sum-reduce within the 32-lane half (xor masks <=16 stay inside)
    s += __shfl_xor(s, 16); s += __shfl_xor(s, 8); s += __shfl_xor(s, 4);
    s += __shfl_xor(s, 2);  s += __shfl_xor(s, 1);
    if (!act) s = -INFINITY;

    const float mn   = fmaxf(m, s);
    const float corr = __expf(m - mn);   // m >= NEG_BIG_ finite -> no NaN
    const float p    = __expf(s - mn);   // s=-inf -> 0
    l = l * corr + p;
    acc.x *= corr; acc.y *= corr; acc.z *= corr; acc.w *= corr;
    if (act) {
      const float* vp = (ki == pos) ? vfresh : (cvh + (size_t)ki * HD_);
      float4 v4 = *(const float4*)(vp + l32 * 4);
      acc.x += p * v4.x; acc.y += p * v4.y; acc.z += p * v4.z; acc.w += p * v4.w;
    }
    m = mn;
  }

  // merge the two halves (each holds a full acc[128] for its key stream)
  const float mo = __shfl_xor(m, 32);
  const float lo = __shfl_xor(l, 32);
  float4 ao;
  ao.x = __shfl_xor(acc.x, 32); ao.y = __shfl_xor(acc.y, 32);
  ao.z = __shfl_xor(acc.z, 32); ao.w = __shfl_xor(acc.w, 32);
  const float mm = fmaxf(m, mo);
  const float w0 = __expf(m - mm), w1 = __expf(mo - mm);
  const float lm = l * w0 + lo * w1;
  float4 am;
  am.x = acc.x * w0 + ao.x * w1; am.y = acc.y * w0 + ao.y * w1;
  am.z = acc.z * w0 + ao.z * w1; am.w = acc.w * w0 + ao.w * w1;

  if (half == 0) {
    *(float4*)(pb + 4 + l32 * 4) = am;
    if (l32 == 0) { pb[0] = mm; pb[1] = lm; }
  }
}

// Merge the 32 split partials per (b,h) into attn output [b][h*128+d].
__global__ __launch_bounds__(128) void attn_combine(
    const float* __restrict__ part, float* __restrict__ attnout)
{
  const int pair = blockIdx.x;
  const int d    = threadIdx.x;
  const float* pb = part + (size_t)pair * NUNIT_ * PSTR_;

  float mg = NEG_BIG_;
  for (int u = 0; u < NUNIT_; ++u) {
    const float lu = pb[u * PSTR_ + 1];
    if (lu > 0.f) mg = fmaxf(mg, pb[u * PSTR_]);
  }
  float ls = 0.f, o = 0.f;
  for (int u = 0; u < NUNIT_; ++u) {
    const float lu = pb[u * PSTR_ + 1];
    if (lu > 0.f) {
      const float wu = __expf(pb[u * PSTR_] - mg);
      ls += lu * wu;
      o  += wu * pb[u * PSTR_ + 4 + d];
    }
  }
  attnout[pair * HD_ + d] = o / ls;
}

extern "C" void kernel_launch(void* const* d_in, const int* in_sizes, int n_in,
                              void* d_out, int out_size, void* d_ws, size_t ws_size,
                              hipStream_t stream) {
  const float* x  = (const float*)d_in[0];
  const float* ck = (const float*)d_in[1];
  const float* cv = (const float*)d_in[2];
  const float* wq = (const float*)d_in[3];
  const float* wk = (const float*)d_in[4];
  const float* wv = (const float*)d_in[5];
  const float* wo = (const float*)d_in[6];
  const int* pos  = (const int*)d_in[7];
  float* out = (float*)d_out;
  float* ws  = (float*)d_ws;

  float* qkv     = ws;                 // 3 * 8 * 4096 floats (q, k, v)
  float* part    = ws + PART_OFF_;     // 256 * 32 * 132 floats
  float* attnout = ws + ATTN_OFF_;     // 8 * 4096 floats
  // total ws use: ~4.7 MB

  gemv_rows<<<3 * 256, 256, 0, stream>>>(wq, wk, wv, x, qkv);
  attn_partial<<<(NPAIR_ * NUNIT_) / 4, 256, 0, stream>>>(qkv, ck, cv, pos, part);
  attn_combine<<<NPAIR_, 128, 0, stream>>>(part, attnout);
  gemv_rows<<<256, 256, 0, stream>>>(wo, wo, wo, attnout, out);
}